// Round 1
// 190.853 us; speedup vs baseline: 1.0119x; 1.0119x over previous
//
#include <hip/hip_runtime.h>
#include <hip/hip_cooperative_groups.h>

namespace cg = cooperative_groups;

#define NN 500000
#define KK 3
#define EE (NN * KK)
#define HH 64
#define NC 8
#define NIN 16
#define EIN 8

#define NBLK 1024
#define NTHR 256
#define STRIDE (NBLK * NTHR)

typedef __attribute__((ext_vector_type(2))) _Float16 h2;
typedef __attribute__((ext_vector_type(2)))  float sf2;
typedef __attribute__((ext_vector_type(8)))  float sf8;
typedef __attribute__((ext_vector_type(16))) float sf16;

using pk_t = decltype(__builtin_amdgcn_cvt_pkrtz(0.f, 0.f));

#if __has_builtin(__builtin_elementwise_fma)
#define PKFMA(a,b,c) __builtin_elementwise_fma((a),(b),(c))
#else
#define PKFMA(a,b,c) ((a)*(b)+(c))
#endif

__device__ __forceinline__ h2 bch2(float f)        { return __builtin_bit_cast(h2, f); }
__device__ __forceinline__ h2 bch2u(unsigned int u){ return __builtin_bit_cast(h2, u); }
__device__ __forceinline__ h2 dup16(float f) {
    return __builtin_bit_cast(h2, __builtin_amdgcn_cvt_pkrtz(f, f));
}
__device__ __forceinline__ unsigned int pkrtz_u(float a, float b) {
    return __builtin_bit_cast(unsigned int, __builtin_amdgcn_cvt_pkrtz(a, b));
}
__device__ __forceinline__ h2 splat_lo(unsigned int u) {
    h2 p = bch2u(u); h2 r; r.x = p.x; r.y = p.x; return r;
}
__device__ __forceinline__ h2 splat_hi(unsigned int u) {
    h2 p = bch2u(u); h2 r; r.x = p.y; r.y = p.y; return r;
}
__device__ __forceinline__ float lo_f32(unsigned int u) { return (float)bch2u(u).x; }
__device__ __forceinline__ float hi_f32(unsigned int u) { return (float)bch2u(u).y; }

__device__ __forceinline__ float fdot2(h2 a, h2 b, float c) {
#if __has_builtin(__builtin_amdgcn_fdot2)
    return __builtin_amdgcn_fdot2(__builtin_bit_cast(pk_t, a),
                                  __builtin_bit_cast(pk_t, b), c, false);
#else
    return c + (float)a.x * (float)b.x + (float)a.y * (float)b.y;
#endif
}
__device__ __forceinline__ h2 lk2(h2 x) {
    h2 c = {(_Float16)0.1f, (_Float16)0.1f};
    return __builtin_elementwise_max(x, x * c);
}
__device__ __forceinline__ float pack2(float a, float b) {
    h2 v; v.x = (_Float16)a; v.y = (_Float16)b;   // RTN conversion for weights
    return __builtin_bit_cast(float, v);
}

// ---------------------------------------------------------------------------
// Shared math bodies (bit-identical to the verified 3-kernel version)
// ---------------------------------------------------------------------------

// message MLP over 3 star edges + update MLP; returns packed new h
__device__ __forceinline__ unsigned int layer_math(
    unsigned int hO,
    unsigned int e0, unsigned int e1, unsigned int e2,
    unsigned int g0, unsigned int g1, unsigned int g2,
    const float* __restrict__ mblk, const float* __restrict__ mb2,
    const float* __restrict__ ublk, const float* __restrict__ ub2)
{
    sf2 mb2v = ((const sf2*)mb2)[0];
    sf2 ub2v = ((const sf2*)ub2)[0];

    h2 e0x = splat_lo(e0), e0y = splat_hi(e0);
    h2 e1x = splat_lo(e1), e1y = splat_hi(e1);
    h2 e2x = splat_lo(e2), e2y = splat_hi(e2);
    h2 n0x = splat_lo(g0), n0y = splat_hi(g0);
    h2 n1x = splat_lo(g1), n1y = splat_hi(g1);
    h2 n2x = splat_lo(g2), n2y = splat_hi(g2);

    const sf16* M = (const sf16*)mblk;
    const sf16* U = (const sf16*)ublk;

    // aggr = (sum_e leaky([e,hn]@W1+b1)) @ W2 + 3*b2  (linearity of segment_sum)
    float a0 = 3.0f * mb2v.x, a1 = 3.0f * mb2v.y;
#pragma unroll 2
    for (int c = 0; c < 8; c++) {
        sf16 A = M[2 * c];
        sf16 B = M[2 * c + 1];
#pragma unroll
        for (int jp = 0; jp < 4; jp++) {
            h2 w0 = bch2(A[jp]), w1 = bch2(A[4 + jp]);
            h2 w2 = bch2(A[8 + jp]), w3 = bch2(A[12 + jp]);
            h2 bb = bch2(B[jp]);
            h2 t0 = PKFMA(e0x, w0, PKFMA(e0y, w1, PKFMA(n0x, w2, PKFMA(n0y, w3, bb))));
            h2 t1 = PKFMA(e1x, w0, PKFMA(e1y, w1, PKFMA(n1x, w2, PKFMA(n1y, w3, bb))));
            h2 t2 = PKFMA(e2x, w0, PKFMA(e2y, w1, PKFMA(n2x, w2, PKFMA(n2y, w3, bb))));
            h2 ts = lk2(t0) + lk2(t1) + lk2(t2);
            a0 = fdot2(ts, bch2(B[4 + jp]), a0);
            a1 = fdot2(ts, bch2(B[8 + jp]), a1);
        }
    }

    // update MLP on concat(h, aggr)
    h2 hx = splat_lo(hO), hy = splat_hi(hO);
    h2 ax = dup16(a0), ay = dup16(a1);
    float u0 = ub2v.x, u1 = ub2v.y;
#pragma unroll 2
    for (int c = 0; c < 8; c++) {
        sf16 A = U[2 * c];
        sf16 B = U[2 * c + 1];
#pragma unroll
        for (int jp = 0; jp < 4; jp++) {
            h2 tt = PKFMA(hx, bch2(A[jp]),
                    PKFMA(hy, bch2(A[4 + jp]),
                    PKFMA(ax, bch2(A[8 + jp]),
                    PKFMA(ay, bch2(A[12 + jp]), bch2(B[jp])))));
            tt = lk2(tt);
            u0 = fdot2(tt, bch2(B[4 + jp]), u0);
            u1 = fdot2(tt, bch2(B[8 + jp]), u1);
        }
    }
    float nh0 = fmaxf(lo_f32(hO) + u0, 0.0f);
    float nh1 = fmaxf(hi_f32(hO) + u1, 0.0f);
    return pkrtz_u(nh0, nh1);
}

// final MLP: packed h -> 8 class scores
__device__ __forceinline__ void final_math(
    unsigned int hU,
    const float* __restrict__ fblk, const float* __restrict__ fb2,
    float* __restrict__ outp)
{
    sf8 fb2v = ((const sf8*)fb2)[0];
    float o[NC];
#pragma unroll
    for (int cc = 0; cc < NC; cc++) o[cc] = fb2v[cc];
    h2 nx = splat_lo(hU), ny = splat_hi(hU);
#pragma unroll 2
    for (int c = 0; c < 8; c++) {
        const float* F = fblk + c * 48;
        sf16 A = ((const sf16*)F)[0];
        sf16 B = ((const sf16*)F)[1];
        sf16 C = ((const sf16*)F)[2];
#pragma unroll
        for (int jp = 0; jp < 4; jp++) {
            h2 w1a = bch2(A[jp]), w1b = bch2(A[4 + jp]), bb = bch2(A[8 + jp]);
            h2 tt = lk2(PKFMA(nx, w1a, PKFMA(ny, w1b, bb)));
#pragma unroll
            for (int cc = 0; cc < NC; cc++) {
                float w = (jp < 2) ? B[(jp & 1) * 8 + cc] : C[(jp & 1) * 8 + cc];
                o[cc] = fdot2(tt, bch2(w), o[cc]);
            }
        }
    }
    float4* op = (float4*)outp;
    op[0] = make_float4(o[0], o[1], o[2], o[3]);
    op[1] = make_float4(o[4], o[5], o[6], o[7]);
}

// P1 per-node work: node projection + 3 edge projections + nbr load
__device__ __forceinline__ void p1_node(
    int i,
    const float* __restrict__ node_feat, const float* __restrict__ edge_attr,
    const int* __restrict__ nbr,
    sf16 wn0, sf16 wn1, sf2 bnv, sf16 wev, sf2 bev,
    unsigned int* __restrict__ hA,
    unsigned int& hs, unsigned int* ep, int* nb)
{
    const float4* x4 = (const float4*)(node_feat + (size_t)i * NIN);
    float4 v0 = x4[0], v1 = x4[1], v2 = x4[2], v3 = x4[3];
    float xs[16] = {v0.x, v0.y, v0.z, v0.w, v1.x, v1.y, v1.z, v1.w,
                    v2.x, v2.y, v2.z, v2.w, v3.x, v3.y, v3.z, v3.w};
    float a0 = bnv.x, a1 = bnv.y;
#pragma unroll
    for (int q = 0; q < 8; q++) {
        a0 = fmaf(xs[q], wn0[2 * q], a0);
        a1 = fmaf(xs[q], wn0[2 * q + 1], a1);
    }
#pragma unroll
    for (int q = 0; q < 8; q++) {
        a0 = fmaf(xs[8 + q], wn1[2 * q], a0);
        a1 = fmaf(xs[8 + q], wn1[2 * q + 1], a1);
    }
    hs = pkrtz_u(a0, a1);
    hA[i] = hs;

    int base = i * KK;
    nb[0] = nbr[base + 0];
    nb[1] = nbr[base + 1];
    nb[2] = nbr[base + 2];

#pragma unroll
    for (int k = 0; k < 3; k++) {
        const float4* e4 = (const float4*)(edge_attr + (size_t)(base + k) * EIN);
        float4 w0 = e4[0], w1 = e4[1];
        float es[8] = {w0.x, w0.y, w0.z, w0.w, w1.x, w1.y, w1.z, w1.w};
        float b0 = bev.x, b1 = bev.y;
#pragma unroll
        for (int q = 0; q < 8; q++) {
            b0 = fmaf(es[q], wev[2 * q], b0);
            b1 = fmaf(es[q], wev[2 * q + 1], b1);
        }
        ep[k] = pkrtz_u(b0, b1);
    }
}

// weight packing (threads 0..39 of block 0)
__device__ __forceinline__ void pack_weights(
    int t,
    const float* __restrict__ msgW1, const float* __restrict__ msgb1, const float* __restrict__ msgW2,
    const float* __restrict__ updW1, const float* __restrict__ updb1, const float* __restrict__ updW2,
    const float* __restrict__ finW1, const float* __restrict__ finb1, const float* __restrict__ finW2,
    float* __restrict__ wpack)
{
    if (t < 32) {
        int l = t >> 4, which = (t >> 3) & 1, c = t & 7;
        const float* W1 = (which ? updW1 : msgW1) + l * 4 * HH;
        const float* b1 = (which ? updb1 : msgb1) + l * HH;
        const float* W2 = (which ? updW2 : msgW2) + l * 2 * HH;
        float* dst = wpack + (l * 2 + which) * 256 + c * 32;
        int j0 = c * 8;
        for (int r = 0; r < 4; r++)
            for (int p = 0; p < 4; p++)
                dst[r * 4 + p] = pack2(W1[r * HH + j0 + 2 * p], W1[r * HH + j0 + 2 * p + 1]);
        for (int p = 0; p < 4; p++) {
            dst[16 + p] = pack2(b1[j0 + 2 * p], b1[j0 + 2 * p + 1]);
            dst[20 + p] = pack2(W2[(j0 + 2 * p) * 2 + 0], W2[(j0 + 2 * p + 1) * 2 + 0]);
            dst[24 + p] = pack2(W2[(j0 + 2 * p) * 2 + 1], W2[(j0 + 2 * p + 1) * 2 + 1]);
            dst[28 + p] = 0.0f;
        }
    } else if (t < 40) {
        int c = t - 32, j0 = c * 8;
        float* dst = wpack + 1024 + c * 48;
        for (int p = 0; p < 4; p++) {
            dst[p]      = pack2(finW1[j0 + 2 * p],      finW1[j0 + 2 * p + 1]);
            dst[4 + p]  = pack2(finW1[HH + j0 + 2 * p], finW1[HH + j0 + 2 * p + 1]);
            dst[8 + p]  = pack2(finb1[j0 + 2 * p],      finb1[j0 + 2 * p + 1]);
            dst[12 + p] = 0.0f;
        }
        for (int jp = 0; jp < 4; jp++)
            for (int cc = 0; cc < NC; cc++)
                dst[16 + jp * 8 + cc] = pack2(finW2[(j0 + 2 * jp) * NC + cc],
                                              finW2[(j0 + 2 * jp + 1) * NC + cc]);
    }
}

// ---------------------------------------------------------------------------
// Fused cooperative kernel: P1 (proj) -> sync -> P2 (layer0) -> sync ->
// P3 (layer1 + final). Each thread owns 2 nodes; edge projections, neighbor
// indices, and self-h live in registers across all phases (no eP buffer,
// nbr read once).
// ---------------------------------------------------------------------------
__global__ __launch_bounds__(NTHR, 4) void fused_kernel(
    const float* __restrict__ node_feat, const float* __restrict__ edge_attr,
    const int* __restrict__ nbr,
    const float* __restrict__ Wn, const float* __restrict__ bn,
    const float* __restrict__ We, const float* __restrict__ be,
    const float* __restrict__ msgW1, const float* __restrict__ msgb1,
    const float* __restrict__ msgW2, const float* __restrict__ msgb2,
    const float* __restrict__ updW1, const float* __restrict__ updb1,
    const float* __restrict__ updW2, const float* __restrict__ updb2,
    const float* __restrict__ finW1, const float* __restrict__ finb1,
    const float* __restrict__ finW2, const float* __restrict__ finb2,
    unsigned int* __restrict__ hA, unsigned int* __restrict__ hB,
    float* __restrict__ wpack, float* __restrict__ out)
{
    cg::grid_group grid = cg::this_grid();
    int tid = blockIdx.x * NTHR + threadIdx.x;

    unsigned int hs[2] = {0u, 0u};
    unsigned int ep[2][3] = {{0u,0u,0u},{0u,0u,0u}};
    int nb[2][3] = {{0,0,0},{0,0,0}};

    // ---- P1: node projection + edge projection (+ weight packing) ----
    {
        const sf16* Wn16 = (const sf16*)Wn;
        sf16 wn0 = Wn16[0], wn1 = Wn16[1];
        sf2  bnv = ((const sf2*)bn)[0];
        sf16 wev = ((const sf16*)We)[0];
        sf2  bev = ((const sf2*)be)[0];
#pragma unroll
        for (int n = 0; n < 2; n++) {
            int i = tid + n * STRIDE;
            if (i < NN)
                p1_node(i, node_feat, edge_attr, nbr, wn0, wn1, bnv, wev, bev,
                        hA, hs[n], ep[n], nb[n]);
        }
        if (blockIdx.x == 0)
            pack_weights(threadIdx.x, msgW1, msgb1, msgW2,
                         updW1, updb1, updW2, finW1, finb1, finW2, wpack);
    }

    grid.sync();

    // ---- P2: layer 0 ----
#pragma unroll
    for (int n = 0; n < 2; n++) {
        int i = tid + n * STRIDE;
        if (i < NN) {
            unsigned int g0 = hA[nb[n][0]], g1 = hA[nb[n][1]], g2 = hA[nb[n][2]];
            hs[n] = layer_math(hs[n], ep[n][0], ep[n][1], ep[n][2], g0, g1, g2,
                               wpack + 0 * 256, msgb2, wpack + 1 * 256, updb2);
            hB[i] = hs[n];
        }
    }

    grid.sync();

    // ---- P3: layer 1 + fused final MLP ----
#pragma unroll
    for (int n = 0; n < 2; n++) {
        int i = tid + n * STRIDE;
        if (i < NN) {
            unsigned int g0 = hB[nb[n][0]], g1 = hB[nb[n][1]], g2 = hB[nb[n][2]];
            unsigned int hU = layer_math(hs[n], ep[n][0], ep[n][1], ep[n][2], g0, g1, g2,
                                         wpack + 2 * 256, msgb2 + 2, wpack + 3 * 256, updb2 + 2);
            final_math(hU, wpack + 1024, finb2, out + (size_t)i * NC);
        }
    }
}

// ---------------------------------------------------------------------------
// Legacy 3-kernel path (verified) — kept as fallback if cooperative launch
// is unavailable under graph capture.
// ---------------------------------------------------------------------------
__global__ __launch_bounds__(256) void prep_kernel(
    const float* __restrict__ node_feat,
    const float* __restrict__ Wn, const float* __restrict__ bn,
    unsigned int* __restrict__ hp,
    const float* __restrict__ msgW1, const float* __restrict__ msgb1, const float* __restrict__ msgW2,
    const float* __restrict__ updW1, const float* __restrict__ updb1, const float* __restrict__ updW2,
    const float* __restrict__ finW1, const float* __restrict__ finb1, const float* __restrict__ finW2,
    float* __restrict__ wpack)
{
    const sf16* Wn16 = (const sf16*)Wn;
    sf16 wn0 = Wn16[0];
    sf16 wn1 = Wn16[1];
    sf2  bnv = ((const sf2*)bn)[0];

    int idx = blockIdx.x * 256 + threadIdx.x;
    if (idx < NN) {
        const float4* x4 = (const float4*)(node_feat + (size_t)idx * NIN);
        float4 v0 = x4[0], v1 = x4[1], v2 = x4[2], v3 = x4[3];
        float xs[16] = {v0.x, v0.y, v0.z, v0.w, v1.x, v1.y, v1.z, v1.w,
                        v2.x, v2.y, v2.z, v2.w, v3.x, v3.y, v3.z, v3.w};
        float a0 = bnv.x, a1 = bnv.y;
#pragma unroll
        for (int i = 0; i < 8; i++) {
            a0 = fmaf(xs[i], wn0[2 * i], a0);
            a1 = fmaf(xs[i], wn0[2 * i + 1], a1);
        }
#pragma unroll
        for (int i = 0; i < 8; i++) {
            a0 = fmaf(xs[8 + i], wn1[2 * i], a0);
            a1 = fmaf(xs[8 + i], wn1[2 * i + 1], a1);
        }
        hp[idx] = pkrtz_u(a0, a1);
    }

    if (blockIdx.x == 0)
        pack_weights(threadIdx.x, msgW1, msgb1, msgW2,
                     updW1, updb1, updW2, finW1, finb1, finW2, wpack);
}

__global__ __launch_bounds__(256) void layer0_kernel(
    const unsigned int* __restrict__ hp_in,
    const float* __restrict__ edge_attr,
    const float* __restrict__ We, const float* __restrict__ be,
    const int* __restrict__ nbr,
    const float* __restrict__ mblk, const float* __restrict__ mb2,
    const float* __restrict__ ublk, const float* __restrict__ ub2,
    unsigned int* __restrict__ hp_out, unsigned int* __restrict__ ep_out)
{
    int i = blockIdx.x * 256 + threadIdx.x;
    if (i >= NN) return;

    sf16 wev = ((const sf16*)We)[0];
    sf2  bev = ((const sf2*)be)[0];

    int base = i * KK;
    unsigned int epk[3];
#pragma unroll
    for (int k = 0; k < 3; k++) {
        const float4* x4 = (const float4*)(edge_attr + (size_t)(base + k) * EIN);
        float4 v0 = x4[0], v1 = x4[1];
        float xs[8] = {v0.x, v0.y, v0.z, v0.w, v1.x, v1.y, v1.z, v1.w};
        float a0 = bev.x, a1 = bev.y;
#pragma unroll
        for (int q = 0; q < 8; q++) {
            a0 = fmaf(xs[q], wev[2 * q], a0);
            a1 = fmaf(xs[q], wev[2 * q + 1], a1);
        }
        epk[k] = pkrtz_u(a0, a1);
        ep_out[base + k] = epk[k];
    }

    unsigned int hO = hp_in[i];
    int n0 = nbr[base + 0], n1 = nbr[base + 1], n2 = nbr[base + 2];
    unsigned int g0 = hp_in[n0], g1 = hp_in[n1], g2 = hp_in[n2];

    hp_out[i] = layer_math(hO, epk[0], epk[1], epk[2], g0, g1, g2, mblk, mb2, ublk, ub2);
}

__global__ __launch_bounds__(256) void layer1_kernel(
    const unsigned int* __restrict__ hp_in, const unsigned int* __restrict__ eP,
    const int* __restrict__ nbr,
    const float* __restrict__ mblk, const float* __restrict__ mb2,
    const float* __restrict__ ublk, const float* __restrict__ ub2,
    const float* __restrict__ fblk, const float* __restrict__ fb2,
    float* __restrict__ out)
{
    int i = blockIdx.x * 256 + threadIdx.x;
    if (i >= NN) return;

    unsigned int hO = hp_in[i];
    int base = i * KK;
    int n0 = nbr[base + 0], n1 = nbr[base + 1], n2 = nbr[base + 2];
    unsigned int g0 = hp_in[n0], g1 = hp_in[n1], g2 = hp_in[n2];
    unsigned int e0 = eP[base + 0], e1 = eP[base + 1], e2 = eP[base + 2];

    unsigned int hU = layer_math(hO, e0, e1, e2, g0, g1, g2, mblk, mb2, ublk, ub2);
    final_math(hU, fblk, fb2, out + (size_t)i * NC);
}

extern "C" void kernel_launch(void* const* d_in, const int* in_sizes, int n_in,
                              void* d_out, int out_size, void* d_ws, size_t ws_size,
                              hipStream_t stream) {
    const float* node_feat = (const float*)d_in[0];
    const float* edge_attr = (const float*)d_in[1];
    const int* edge_index = (const int*)d_in[2];
    // d_in[3] = batch (unused)
    const float* Wn = (const float*)d_in[4];
    const float* bn = (const float*)d_in[5];
    const float* We = (const float*)d_in[6];
    const float* be = (const float*)d_in[7];
    const float* msgW1 = (const float*)d_in[8];
    const float* msgb1 = (const float*)d_in[9];
    const float* msgW2 = (const float*)d_in[10];
    const float* msgb2 = (const float*)d_in[11];
    const float* updW1 = (const float*)d_in[12];
    const float* updb1 = (const float*)d_in[13];
    const float* updW2 = (const float*)d_in[14];
    const float* updb2 = (const float*)d_in[15];
    const float* finW1 = (const float*)d_in[16];
    const float* finb1 = (const float*)d_in[17];
    const float* finW2 = (const float*)d_in[18];
    const float* finb2 = (const float*)d_in[19];
    float* out = (float*)d_out;

    const int* nbr = edge_index + EE;  // edge_index[1] row

    char* ws = (char*)d_ws;
    unsigned int* hA = (unsigned int*)ws;                              // NN u32 (2 MB)
    unsigned int* hB = (unsigned int*)(ws + (size_t)NN * 4);           // NN u32 (2 MB)
    unsigned int* eP = (unsigned int*)(ws + (size_t)NN * 8);           // EE u32 (6 MB, legacy only)
    float* wpack = (float*)(ws + (size_t)NN * 8 + (size_t)EE * 4);     // ~5.6 KB

    static int coop_ok = -1;
    if (coop_ok < 0) {
        int v = 0;
        if (hipDeviceGetAttribute(&v, hipDeviceAttributeCooperativeLaunch, 0) != hipSuccess)
            v = 0;
        coop_ok = v;
    }

    if (coop_ok) {
        void* args[] = {
            (void*)&node_feat, (void*)&edge_attr, (void*)&nbr,
            (void*)&Wn, (void*)&bn, (void*)&We, (void*)&be,
            (void*)&msgW1, (void*)&msgb1, (void*)&msgW2, (void*)&msgb2,
            (void*)&updW1, (void*)&updb1, (void*)&updW2, (void*)&updb2,
            (void*)&finW1, (void*)&finb1, (void*)&finW2, (void*)&finb2,
            (void*)&hA, (void*)&hB, (void*)&wpack, (void*)&out
        };
        hipError_t err = hipLaunchCooperativeKernel((const void*)fused_kernel,
                                                    dim3(NBLK), dim3(NTHR),
                                                    args, 0, stream);
        if (err == hipSuccess) return;
        coop_ok = 0;  // fall through to legacy path
    }

    const int threads = 256;
    int grid = (NN + threads - 1) / threads;

    prep_kernel<<<grid, threads, 0, stream>>>(
        node_feat, Wn, bn, hA,
        msgW1, msgb1, msgW2, updW1, updb1, updW2,
        finW1, finb1, finW2, wpack);

    layer0_kernel<<<grid, threads, 0, stream>>>(
        hA, edge_attr, We, be, nbr,
        wpack + 0 * 256, msgb2,
        wpack + 1 * 256, updb2,
        hB, eP);

    layer1_kernel<<<grid, threads, 0, stream>>>(
        hB, eP, nbr,
        wpack + 2 * 256, msgb2 + 2,
        wpack + 3 * 256, updb2 + 2,
        wpack + 1024, finb2, out);
}

// Round 2
// 190.441 us; speedup vs baseline: 1.0141x; 1.0022x over previous
//
#include <hip/hip_runtime.h>
#include <hip/hip_cooperative_groups.h>

namespace cg = cooperative_groups;

#define NN 500000
#define KK 3
#define EE (NN * KK)
#define HH 64
#define NC 8
#define NIN 16
#define EIN 8

#define NTHR 256

typedef __attribute__((ext_vector_type(2))) _Float16 h2;
typedef __attribute__((ext_vector_type(2)))  float sf2;
typedef __attribute__((ext_vector_type(8)))  float sf8;
typedef __attribute__((ext_vector_type(16))) float sf16;

using pk_t = decltype(__builtin_amdgcn_cvt_pkrtz(0.f, 0.f));

#if __has_builtin(__builtin_elementwise_fma)
#define PKFMA(a,b,c) __builtin_elementwise_fma((a),(b),(c))
#else
#define PKFMA(a,b,c) ((a)*(b)+(c))
#endif

__device__ __forceinline__ h2 bch2(float f)        { return __builtin_bit_cast(h2, f); }
__device__ __forceinline__ h2 bch2u(unsigned int u){ return __builtin_bit_cast(h2, u); }
__device__ __forceinline__ h2 dup16(float f) {
    return __builtin_bit_cast(h2, __builtin_amdgcn_cvt_pkrtz(f, f));
}
__device__ __forceinline__ unsigned int pkrtz_u(float a, float b) {
    return __builtin_bit_cast(unsigned int, __builtin_amdgcn_cvt_pkrtz(a, b));
}
__device__ __forceinline__ h2 splat_lo(unsigned int u) {
    h2 p = bch2u(u); h2 r; r.x = p.x; r.y = p.x; return r;
}
__device__ __forceinline__ h2 splat_hi(unsigned int u) {
    h2 p = bch2u(u); h2 r; r.x = p.y; r.y = p.y; return r;
}
__device__ __forceinline__ float lo_f32(unsigned int u) { return (float)bch2u(u).x; }
__device__ __forceinline__ float hi_f32(unsigned int u) { return (float)bch2u(u).y; }

__device__ __forceinline__ float fdot2(h2 a, h2 b, float c) {
#if __has_builtin(__builtin_amdgcn_fdot2)
    return __builtin_amdgcn_fdot2(__builtin_bit_cast(pk_t, a),
                                  __builtin_bit_cast(pk_t, b), c, false);
#else
    return c + (float)a.x * (float)b.x + (float)a.y * (float)b.y;
#endif
}
__device__ __forceinline__ h2 lk2(h2 x) {
    h2 c = {(_Float16)0.1f, (_Float16)0.1f};
    return __builtin_elementwise_max(x, x * c);
}
__device__ __forceinline__ float pack2(float a, float b) {
    h2 v; v.x = (_Float16)a; v.y = (_Float16)b;   // RTN conversion for weights
    return __builtin_bit_cast(float, v);
}

// ---------------------------------------------------------------------------
// Shared math bodies (bit-identical to the verified 3-kernel version)
// ---------------------------------------------------------------------------

__device__ __forceinline__ unsigned int layer_math(
    unsigned int hO,
    unsigned int e0, unsigned int e1, unsigned int e2,
    unsigned int g0, unsigned int g1, unsigned int g2,
    const float* __restrict__ mblk, const float* __restrict__ mb2,
    const float* __restrict__ ublk, const float* __restrict__ ub2)
{
    sf2 mb2v = ((const sf2*)mb2)[0];
    sf2 ub2v = ((const sf2*)ub2)[0];

    h2 e0x = splat_lo(e0), e0y = splat_hi(e0);
    h2 e1x = splat_lo(e1), e1y = splat_hi(e1);
    h2 e2x = splat_lo(e2), e2y = splat_hi(e2);
    h2 n0x = splat_lo(g0), n0y = splat_hi(g0);
    h2 n1x = splat_lo(g1), n1y = splat_hi(g1);
    h2 n2x = splat_lo(g2), n2y = splat_hi(g2);

    const sf16* M = (const sf16*)mblk;
    const sf16* U = (const sf16*)ublk;

    // aggr = (sum_e leaky([e,hn]@W1+b1)) @ W2 + 3*b2  (linearity of segment_sum)
    float a0 = 3.0f * mb2v.x, a1 = 3.0f * mb2v.y;
#pragma unroll 2
    for (int c = 0; c < 8; c++) {
        sf16 A = M[2 * c];
        sf16 B = M[2 * c + 1];
#pragma unroll
        for (int jp = 0; jp < 4; jp++) {
            h2 w0 = bch2(A[jp]), w1 = bch2(A[4 + jp]);
            h2 w2 = bch2(A[8 + jp]), w3 = bch2(A[12 + jp]);
            h2 bb = bch2(B[jp]);
            h2 t0 = PKFMA(e0x, w0, PKFMA(e0y, w1, PKFMA(n0x, w2, PKFMA(n0y, w3, bb))));
            h2 t1 = PKFMA(e1x, w0, PKFMA(e1y, w1, PKFMA(n1x, w2, PKFMA(n1y, w3, bb))));
            h2 t2 = PKFMA(e2x, w0, PKFMA(e2y, w1, PKFMA(n2x, w2, PKFMA(n2y, w3, bb))));
            h2 ts = lk2(t0) + lk2(t1) + lk2(t2);
            a0 = fdot2(ts, bch2(B[4 + jp]), a0);
            a1 = fdot2(ts, bch2(B[8 + jp]), a1);
        }
    }

    // update MLP on concat(h, aggr)
    h2 hx = splat_lo(hO), hy = splat_hi(hO);
    h2 ax = dup16(a0), ay = dup16(a1);
    float u0 = ub2v.x, u1 = ub2v.y;
#pragma unroll 2
    for (int c = 0; c < 8; c++) {
        sf16 A = U[2 * c];
        sf16 B = U[2 * c + 1];
#pragma unroll
        for (int jp = 0; jp < 4; jp++) {
            h2 tt = PKFMA(hx, bch2(A[jp]),
                    PKFMA(hy, bch2(A[4 + jp]),
                    PKFMA(ax, bch2(A[8 + jp]),
                    PKFMA(ay, bch2(A[12 + jp]), bch2(B[jp])))));
            tt = lk2(tt);
            u0 = fdot2(tt, bch2(B[4 + jp]), u0);
            u1 = fdot2(tt, bch2(B[8 + jp]), u1);
        }
    }
    float nh0 = fmaxf(lo_f32(hO) + u0, 0.0f);
    float nh1 = fmaxf(hi_f32(hO) + u1, 0.0f);
    return pkrtz_u(nh0, nh1);
}

__device__ __forceinline__ void final_math(
    unsigned int hU,
    const float* __restrict__ fblk, const float* __restrict__ fb2,
    float* __restrict__ outp)
{
    sf8 fb2v = ((const sf8*)fb2)[0];
    float o[NC];
#pragma unroll
    for (int cc = 0; cc < NC; cc++) o[cc] = fb2v[cc];
    h2 nx = splat_lo(hU), ny = splat_hi(hU);
#pragma unroll 2
    for (int c = 0; c < 8; c++) {
        const float* F = fblk + c * 48;
        sf16 A = ((const sf16*)F)[0];
        sf16 B = ((const sf16*)F)[1];
        sf16 C = ((const sf16*)F)[2];
#pragma unroll
        for (int jp = 0; jp < 4; jp++) {
            h2 w1a = bch2(A[jp]), w1b = bch2(A[4 + jp]), bb = bch2(A[8 + jp]);
            h2 tt = lk2(PKFMA(nx, w1a, PKFMA(ny, w1b, bb)));
#pragma unroll
            for (int cc = 0; cc < NC; cc++) {
                float w = (jp < 2) ? B[(jp & 1) * 8 + cc] : C[(jp & 1) * 8 + cc];
                o[cc] = fdot2(tt, bch2(w), o[cc]);
            }
        }
    }
    float4* op = (float4*)outp;
    op[0] = make_float4(o[0], o[1], o[2], o[3]);
    op[1] = make_float4(o[4], o[5], o[6], o[7]);
}

__device__ __forceinline__ void p1_node(
    int i,
    const float* __restrict__ node_feat, const float* __restrict__ edge_attr,
    const int* __restrict__ nbr,
    sf16 wn0, sf16 wn1, sf2 bnv, sf16 wev, sf2 bev,
    unsigned int* __restrict__ hA,
    unsigned int& hs, unsigned int* ep, int* nb)
{
    const float4* x4 = (const float4*)(node_feat + (size_t)i * NIN);
    float4 v0 = x4[0], v1 = x4[1], v2 = x4[2], v3 = x4[3];
    float xs[16] = {v0.x, v0.y, v0.z, v0.w, v1.x, v1.y, v1.z, v1.w,
                    v2.x, v2.y, v2.z, v2.w, v3.x, v3.y, v3.z, v3.w};
    float a0 = bnv.x, a1 = bnv.y;
#pragma unroll
    for (int q = 0; q < 8; q++) {
        a0 = fmaf(xs[q], wn0[2 * q], a0);
        a1 = fmaf(xs[q], wn0[2 * q + 1], a1);
    }
#pragma unroll
    for (int q = 0; q < 8; q++) {
        a0 = fmaf(xs[8 + q], wn1[2 * q], a0);
        a1 = fmaf(xs[8 + q], wn1[2 * q + 1], a1);
    }
    hs = pkrtz_u(a0, a1);
    hA[i] = hs;

    int base = i * KK;
    nb[0] = nbr[base + 0];
    nb[1] = nbr[base + 1];
    nb[2] = nbr[base + 2];

#pragma unroll
    for (int k = 0; k < 3; k++) {
        const float4* e4 = (const float4*)(edge_attr + (size_t)(base + k) * EIN);
        float4 w0 = e4[0], w1 = e4[1];
        float es[8] = {w0.x, w0.y, w0.z, w0.w, w1.x, w1.y, w1.z, w1.w};
        float b0 = bev.x, b1 = bev.y;
#pragma unroll
        for (int q = 0; q < 8; q++) {
            b0 = fmaf(es[q], wev[2 * q], b0);
            b1 = fmaf(es[q], wev[2 * q + 1], b1);
        }
        ep[k] = pkrtz_u(b0, b1);
    }
}

__device__ __forceinline__ void pack_weights(
    int t,
    const float* __restrict__ msgW1, const float* __restrict__ msgb1, const float* __restrict__ msgW2,
    const float* __restrict__ updW1, const float* __restrict__ updb1, const float* __restrict__ updW2,
    const float* __restrict__ finW1, const float* __restrict__ finb1, const float* __restrict__ finW2,
    float* __restrict__ wpack)
{
    if (t < 32) {
        int l = t >> 4, which = (t >> 3) & 1, c = t & 7;
        const float* W1 = (which ? updW1 : msgW1) + l * 4 * HH;
        const float* b1 = (which ? updb1 : msgb1) + l * HH;
        const float* W2 = (which ? updW2 : msgW2) + l * 2 * HH;
        float* dst = wpack + (l * 2 + which) * 256 + c * 32;
        int j0 = c * 8;
        for (int r = 0; r < 4; r++)
            for (int p = 0; p < 4; p++)
                dst[r * 4 + p] = pack2(W1[r * HH + j0 + 2 * p], W1[r * HH + j0 + 2 * p + 1]);
        for (int p = 0; p < 4; p++) {
            dst[16 + p] = pack2(b1[j0 + 2 * p], b1[j0 + 2 * p + 1]);
            dst[20 + p] = pack2(W2[(j0 + 2 * p) * 2 + 0], W2[(j0 + 2 * p + 1) * 2 + 0]);
            dst[24 + p] = pack2(W2[(j0 + 2 * p) * 2 + 1], W2[(j0 + 2 * p + 1) * 2 + 1]);
            dst[28 + p] = 0.0f;
        }
    } else if (t < 40) {
        int c = t - 32, j0 = c * 8;
        float* dst = wpack + 1024 + c * 48;
        for (int p = 0; p < 4; p++) {
            dst[p]      = pack2(finW1[j0 + 2 * p],      finW1[j0 + 2 * p + 1]);
            dst[4 + p]  = pack2(finW1[HH + j0 + 2 * p], finW1[HH + j0 + 2 * p + 1]);
            dst[8 + p]  = pack2(finb1[j0 + 2 * p],      finb1[j0 + 2 * p + 1]);
            dst[12 + p] = 0.0f;
        }
        for (int jp = 0; jp < 4; jp++)
            for (int cc = 0; cc < NC; cc++)
                dst[16 + jp * 8 + cc] = pack2(finW2[(j0 + 2 * jp) * NC + cc],
                                              finW2[(j0 + 2 * jp + 1) * NC + cc]);
    }
}

// ---------------------------------------------------------------------------
// Fused cooperative kernel, templated on nodes-per-thread and min blocks/CU.
// NPT=1 / 8 blocks-per-CU is the primary config: ~1954 blocks, 8 waves/SIMD,
// one node per thread -> max TLP for hiding gather latency.
// ---------------------------------------------------------------------------
template<int NPT, int MINB>
__global__ __launch_bounds__(NTHR, MINB) void fused_kernel(
    const float* __restrict__ node_feat, const float* __restrict__ edge_attr,
    const int* __restrict__ nbr,
    const float* __restrict__ Wn, const float* __restrict__ bn,
    const float* __restrict__ We, const float* __restrict__ be,
    const float* __restrict__ msgW1, const float* __restrict__ msgb1,
    const float* __restrict__ msgW2, const float* __restrict__ msgb2,
    const float* __restrict__ updW1, const float* __restrict__ updb1,
    const float* __restrict__ updW2, const float* __restrict__ updb2,
    const float* __restrict__ finW1, const float* __restrict__ finb1,
    const float* __restrict__ finW2, const float* __restrict__ finb2,
    unsigned int* __restrict__ hA, unsigned int* __restrict__ hB,
    float* __restrict__ wpack, float* __restrict__ out)
{
    cg::grid_group grid = cg::this_grid();
    const int tid = blockIdx.x * NTHR + threadIdx.x;
    const int stride = gridDim.x * NTHR;

    unsigned int hs[NPT];
    unsigned int ep[NPT][3];
    int nb[NPT][3];
#pragma unroll
    for (int n = 0; n < NPT; n++) {
        hs[n] = 0u;
        ep[n][0] = ep[n][1] = ep[n][2] = 0u;
        nb[n][0] = nb[n][1] = nb[n][2] = 0;
    }

    // ---- P1: node projection + edge projection (+ weight packing) ----
    {
        const sf16* Wn16 = (const sf16*)Wn;
        sf16 wn0 = Wn16[0], wn1 = Wn16[1];
        sf2  bnv = ((const sf2*)bn)[0];
        sf16 wev = ((const sf16*)We)[0];
        sf2  bev = ((const sf2*)be)[0];
#pragma unroll
        for (int n = 0; n < NPT; n++) {
            int i = tid + n * stride;
            if (i < NN)
                p1_node(i, node_feat, edge_attr, nbr, wn0, wn1, bnv, wev, bev,
                        hA, hs[n], ep[n], nb[n]);
        }
        if (blockIdx.x == 0)
            pack_weights(threadIdx.x, msgW1, msgb1, msgW2,
                         updW1, updb1, updW2, finW1, finb1, finW2, wpack);
    }

    grid.sync();

    // ---- P2: layer 0 ----
#pragma unroll
    for (int n = 0; n < NPT; n++) {
        int i = tid + n * stride;
        if (i < NN) {
            unsigned int g0 = hA[nb[n][0]], g1 = hA[nb[n][1]], g2 = hA[nb[n][2]];
            hs[n] = layer_math(hs[n], ep[n][0], ep[n][1], ep[n][2], g0, g1, g2,
                               wpack + 0 * 256, msgb2, wpack + 1 * 256, updb2);
            hB[i] = hs[n];
        }
    }

    grid.sync();

    // ---- P3: layer 1 + fused final MLP ----
#pragma unroll
    for (int n = 0; n < NPT; n++) {
        int i = tid + n * stride;
        if (i < NN) {
            unsigned int g0 = hB[nb[n][0]], g1 = hB[nb[n][1]], g2 = hB[nb[n][2]];
            unsigned int hU = layer_math(hs[n], ep[n][0], ep[n][1], ep[n][2], g0, g1, g2,
                                         wpack + 2 * 256, msgb2 + 2, wpack + 3 * 256, updb2 + 2);
            final_math(hU, wpack + 1024, finb2, out + (size_t)i * NC);
        }
    }
}

// ---------------------------------------------------------------------------
// Legacy 3-kernel path (verified) — fallback if cooperative launch is
// unavailable.
// ---------------------------------------------------------------------------
__global__ __launch_bounds__(256) void prep_kernel(
    const float* __restrict__ node_feat,
    const float* __restrict__ Wn, const float* __restrict__ bn,
    unsigned int* __restrict__ hp,
    const float* __restrict__ msgW1, const float* __restrict__ msgb1, const float* __restrict__ msgW2,
    const float* __restrict__ updW1, const float* __restrict__ updb1, const float* __restrict__ updW2,
    const float* __restrict__ finW1, const float* __restrict__ finb1, const float* __restrict__ finW2,
    float* __restrict__ wpack)
{
    const sf16* Wn16 = (const sf16*)Wn;
    sf16 wn0 = Wn16[0];
    sf16 wn1 = Wn16[1];
    sf2  bnv = ((const sf2*)bn)[0];

    int idx = blockIdx.x * 256 + threadIdx.x;
    if (idx < NN) {
        const float4* x4 = (const float4*)(node_feat + (size_t)idx * NIN);
        float4 v0 = x4[0], v1 = x4[1], v2 = x4[2], v3 = x4[3];
        float xs[16] = {v0.x, v0.y, v0.z, v0.w, v1.x, v1.y, v1.z, v1.w,
                        v2.x, v2.y, v2.z, v2.w, v3.x, v3.y, v3.z, v3.w};
        float a0 = bnv.x, a1 = bnv.y;
#pragma unroll
        for (int i = 0; i < 8; i++) {
            a0 = fmaf(xs[i], wn0[2 * i], a0);
            a1 = fmaf(xs[i], wn0[2 * i + 1], a1);
        }
#pragma unroll
        for (int i = 0; i < 8; i++) {
            a0 = fmaf(xs[8 + i], wn1[2 * i], a0);
            a1 = fmaf(xs[8 + i], wn1[2 * i + 1], a1);
        }
        hp[idx] = pkrtz_u(a0, a1);
    }

    if (blockIdx.x == 0)
        pack_weights(threadIdx.x, msgW1, msgb1, msgW2,
                     updW1, updb1, updW2, finW1, finb1, finW2, wpack);
}

__global__ __launch_bounds__(256) void layer0_kernel(
    const unsigned int* __restrict__ hp_in,
    const float* __restrict__ edge_attr,
    const float* __restrict__ We, const float* __restrict__ be,
    const int* __restrict__ nbr,
    const float* __restrict__ mblk, const float* __restrict__ mb2,
    const float* __restrict__ ublk, const float* __restrict__ ub2,
    unsigned int* __restrict__ hp_out, unsigned int* __restrict__ ep_out)
{
    int i = blockIdx.x * 256 + threadIdx.x;
    if (i >= NN) return;

    sf16 wev = ((const sf16*)We)[0];
    sf2  bev = ((const sf2*)be)[0];

    int base = i * KK;
    unsigned int epk[3];
#pragma unroll
    for (int k = 0; k < 3; k++) {
        const float4* x4 = (const float4*)(edge_attr + (size_t)(base + k) * EIN);
        float4 v0 = x4[0], v1 = x4[1];
        float xs[8] = {v0.x, v0.y, v0.z, v0.w, v1.x, v1.y, v1.z, v1.w};
        float a0 = bev.x, a1 = bev.y;
#pragma unroll
        for (int q = 0; q < 8; q++) {
            a0 = fmaf(xs[q], wev[2 * q], a0);
            a1 = fmaf(xs[q], wev[2 * q + 1], a1);
        }
        epk[k] = pkrtz_u(a0, a1);
        ep_out[base + k] = epk[k];
    }

    unsigned int hO = hp_in[i];
    int n0 = nbr[base + 0], n1 = nbr[base + 1], n2 = nbr[base + 2];
    unsigned int g0 = hp_in[n0], g1 = hp_in[n1], g2 = hp_in[n2];

    hp_out[i] = layer_math(hO, epk[0], epk[1], epk[2], g0, g1, g2, mblk, mb2, ublk, ub2);
}

__global__ __launch_bounds__(256) void layer1_kernel(
    const unsigned int* __restrict__ hp_in, const unsigned int* __restrict__ eP,
    const int* __restrict__ nbr,
    const float* __restrict__ mblk, const float* __restrict__ mb2,
    const float* __restrict__ ublk, const float* __restrict__ ub2,
    const float* __restrict__ fblk, const float* __restrict__ fb2,
    float* __restrict__ out)
{
    int i = blockIdx.x * 256 + threadIdx.x;
    if (i >= NN) return;

    unsigned int hO = hp_in[i];
    int base = i * KK;
    int n0 = nbr[base + 0], n1 = nbr[base + 1], n2 = nbr[base + 2];
    unsigned int g0 = hp_in[n0], g1 = hp_in[n1], g2 = hp_in[n2];
    unsigned int e0 = eP[base + 0], e1 = eP[base + 1], e2 = eP[base + 2];

    unsigned int hU = layer_math(hO, e0, e1, e2, g0, g1, g2, mblk, mb2, ublk, ub2);
    final_math(hU, fblk, fb2, out + (size_t)i * NC);
}

extern "C" void kernel_launch(void* const* d_in, const int* in_sizes, int n_in,
                              void* d_out, int out_size, void* d_ws, size_t ws_size,
                              hipStream_t stream) {
    const float* node_feat = (const float*)d_in[0];
    const float* edge_attr = (const float*)d_in[1];
    const int* edge_index = (const int*)d_in[2];
    // d_in[3] = batch (unused)
    const float* Wn = (const float*)d_in[4];
    const float* bn = (const float*)d_in[5];
    const float* We = (const float*)d_in[6];
    const float* be = (const float*)d_in[7];
    const float* msgW1 = (const float*)d_in[8];
    const float* msgb1 = (const float*)d_in[9];
    const float* msgW2 = (const float*)d_in[10];
    const float* msgb2 = (const float*)d_in[11];
    const float* updW1 = (const float*)d_in[12];
    const float* updb1 = (const float*)d_in[13];
    const float* updW2 = (const float*)d_in[14];
    const float* updb2 = (const float*)d_in[15];
    const float* finW1 = (const float*)d_in[16];
    const float* finb1 = (const float*)d_in[17];
    const float* finW2 = (const float*)d_in[18];
    const float* finb2 = (const float*)d_in[19];
    float* out = (float*)d_out;

    const int* nbr = edge_index + EE;  // edge_index[1] row

    char* ws = (char*)d_ws;
    unsigned int* hA = (unsigned int*)ws;                              // NN u32 (2 MB)
    unsigned int* hB = (unsigned int*)(ws + (size_t)NN * 4);           // NN u32 (2 MB)
    unsigned int* eP = (unsigned int*)(ws + (size_t)NN * 8);           // EE u32 (6 MB, legacy only)
    float* wpack = (float*)(ws + (size_t)NN * 8 + (size_t)EE * 4);     // ~5.6 KB

    const int G_FULL = (NN + NTHR - 1) / NTHR;   // 1954: 1 node/thread
    const int G_HALF = 1024;                     // 2 nodes/thread fallback

    // mode: -1 unresolved, 1 = coop NPT=1 @ G_FULL, 2 = coop NPT=2 @ G_HALF,
    //        0 = legacy 3-kernel
    static int mode = -1;
    if (mode < 0) {
        int coop = 0, ncu = 0;
        if (hipDeviceGetAttribute(&coop, hipDeviceAttributeCooperativeLaunch, 0) != hipSuccess)
            coop = 0;
        if (hipDeviceGetAttribute(&ncu, hipDeviceAttributeMultiprocessorCount, 0) != hipSuccess)
            ncu = 0;
        mode = 0;
        if (coop && ncu > 0) {
            int bpc1 = 0;
            if (hipOccupancyMaxActiveBlocksPerMultiprocessor(
                    &bpc1, fused_kernel<1, 8>, NTHR, 0) == hipSuccess &&
                bpc1 * ncu >= G_FULL) {
                mode = 1;
            } else {
                int bpc2 = 0;
                if (hipOccupancyMaxActiveBlocksPerMultiprocessor(
                        &bpc2, fused_kernel<2, 4>, NTHR, 0) == hipSuccess &&
                    bpc2 * ncu >= G_HALF) {
                    mode = 2;
                }
            }
        }
    }

    if (mode == 1 || mode == 2) {
        void* args[] = {
            (void*)&node_feat, (void*)&edge_attr, (void*)&nbr,
            (void*)&Wn, (void*)&bn, (void*)&We, (void*)&be,
            (void*)&msgW1, (void*)&msgb1, (void*)&msgW2, (void*)&msgb2,
            (void*)&updW1, (void*)&updb1, (void*)&updW2, (void*)&updb2,
            (void*)&finW1, (void*)&finb1, (void*)&finW2, (void*)&finb2,
            (void*)&hA, (void*)&hB, (void*)&wpack, (void*)&out
        };
        const void* fn = (mode == 1)
            ? reinterpret_cast<const void*>(&fused_kernel<1, 8>)
            : reinterpret_cast<const void*>(&fused_kernel<2, 4>);
        int grid = (mode == 1) ? G_FULL : G_HALF;
        hipError_t err = hipLaunchCooperativeKernel(fn, dim3(grid), dim3(NTHR),
                                                    args, 0, stream);
        if (err == hipSuccess) return;
        mode = 0;  // fall through to legacy path
    }

    const int threads = 256;
    int grid = (NN + threads - 1) / threads;

    prep_kernel<<<grid, threads, 0, stream>>>(
        node_feat, Wn, bn, hA,
        msgW1, msgb1, msgW2, updW1, updb1, updW2,
        finW1, finb1, finW2, wpack);

    layer0_kernel<<<grid, threads, 0, stream>>>(
        hA, edge_attr, We, be, nbr,
        wpack + 0 * 256, msgb2,
        wpack + 1 * 256, updb2,
        hB, eP);

    layer1_kernel<<<grid, threads, 0, stream>>>(
        hB, eP, nbr,
        wpack + 2 * 256, msgb2 + 2,
        wpack + 3 * 256, updb2 + 2,
        wpack + 1024, finb2, out);
}